// Round 7
// baseline (308.314 us; speedup 1.0000x reference)
//
#include <hip/hip_runtime.h>

#define IH 4096
#define IW 4096
#define KH 16
#define KW 16
#define OH 4081
#define OW 4081

#define TBC 128       // output cols per block
#define STEP 64       // output rows per pipeline step
#define NSTEP 4       // steps per block -> 256 output rows per block
#define RING 144      // LDS ring rows = 80 (window) + 64 (prefetch)
#define LSTR 168      // shorts per ring row = 336 B; odd 16B-chunk count ->
                      // bank rotation covers all 8 quads -> conflict-free b128
#define CHW 18        // 8-col chunks per staged row (144 cols)

typedef short bf16x8 __attribute__((ext_vector_type(8)));
typedef float f32x16 __attribute__((ext_vector_type(16)));

static __device__ __forceinline__ unsigned int f2bf(float f) {
    unsigned int u = __float_as_uint(f);
    return (u + 0x7FFFu + ((u >> 16) & 1u)) >> 16;   // RTNE
}

// Coalesced B layout: Bt[(u*3 + c)*512 + lane*8 + j], lane = hi*32 + n,
// value = w[u][vp - n], vp = c*16 + hi*8 + j  (0 outside band). 48 KB.
__global__ void build_B(const float* __restrict__ wgt, unsigned short* __restrict__ Bt) {
    int idx = blockIdx.x * 256 + threadIdx.x;        // 0..24575
    if (idx >= 16 * 3 * 512) return;
    int j    = idx & 7;
    int lane = (idx >> 3) & 63;
    int n    = lane & 31;
    int hi   = lane >> 5;
    int c    = (idx >> 9) % 3;
    int u    = idx / 1536;
    int vp   = c * 16 + hi * 8 + j;
    int t    = vp - n;
    float val = (t >= 0 && t < KW) ? wgt[u * KW + t] : 0.0f;
    Bt[idx] = (unsigned short)f2bf(val);
}

__global__ __launch_bounds__(512, 4)
void conv_pipe(const float* __restrict__ x,
               const unsigned short* __restrict__ Bt,
               const float* __restrict__ bias,
               float* __restrict__ out) {
    __shared__ unsigned short ring[RING * LSTR];     // 48384 B -> 2-3 blocks/CU

    const int tid  = threadIdx.x;
    const int lane = tid & 63;
    const int wv   = tid >> 6;       // 0..7
    const int rb   = wv & 1;         // row-group (32 rows)
    const int cb   = wv >> 1;        // col-group (32 cols), 0..3
    const int m    = lane & 31;
    const int hi   = lane >> 5;
    const int gx0  = blockIdx.x * TBC;
    const int oy0  = blockIdx.y * (STEP * NSTEP);

    // ---- prologue: stage input rows [oy0, oy0+80) ----
    for (int idx = tid; idx < 80 * CHW; idx += 512) {
        int row = idx / CHW;
        int c   = idx - row * CHW;
        int gy  = oy0 + row;
        int gx  = gx0 + 8 * c;
        float4 q0 = make_float4(0.f, 0.f, 0.f, 0.f);
        float4 q1 = q0;
        if (gy < IH && gx < IW) {
            q0 = *reinterpret_cast<const float4*>(x + (size_t)gy * IW + gx);
            q1 = *reinterpret_cast<const float4*>(x + (size_t)gy * IW + gx + 4);
        }
        uint4 p;
        p.x = f2bf(q0.x) | (f2bf(q0.y) << 16);
        p.y = f2bf(q0.z) | (f2bf(q0.w) << 16);
        p.z = f2bf(q1.x) | (f2bf(q1.y) << 16);
        p.w = f2bf(q1.z) | (f2bf(q1.w) << 16);
        *reinterpret_cast<uint4*>(&ring[row * LSTR + c * 8]) = p;
    }
    __syncthreads();

    const unsigned short* Blane = Bt + lane * 8;     // wave-contiguous 1 KB fetch
    const int  cA = 4 * cb + hi;                     // base 16B-chunk in ring row
    const float bv = bias[0];

    for (int s = 0; s < NSTEP; ++s) {
        // ---- (a) issue prefetch loads for rows [64s+80, 64s+144) ----
        float4 p0[3], p1[3];
        int pring[3], pcc[3];
        bool pval[3];
        if (s + 1 < NSTEP) {
#pragma unroll
            for (int k = 0; k < 3; ++k) {
                int idx  = tid + k * 512;
                bool v   = idx < STEP * CHW;         // 1152
                int row  = idx / CHW;                // 0..63
                int c    = idx - row * CHW;
                int woff = 64 * s + 80 + row;
                int rr   = woff - (woff >= RING ? RING : 0);
                int gy   = oy0 + woff;
                int gx   = gx0 + 8 * c;
                pring[k] = rr; pcc[k] = c; pval[k] = v;
                float4 q0 = make_float4(0.f, 0.f, 0.f, 0.f);
                float4 q1 = q0;
                if (v && gy < IH && gx < IW) {
                    q0 = *reinterpret_cast<const float4*>(x + (size_t)gy * IW + gx);
                    q1 = *reinterpret_cast<const float4*>(x + (size_t)gy * IW + gx + 4);
                }
                p0[k] = q0; p1[k] = q1;
            }
        }

        // ---- (b) K-loop: 16 u x (3 a-reads + 3 MFMAs), B register rotation ----
        f32x16 acc = {0,0,0,0,0,0,0,0,0,0,0,0,0,0,0,0};
        bf16x8 bc0 = *reinterpret_cast<const bf16x8*>(Blane + 0);
        bf16x8 bc1 = *reinterpret_cast<const bf16x8*>(Blane + 512);
        bf16x8 bc2 = *reinterpret_cast<const bf16x8*>(Blane + 1024);

#pragma unroll
        for (int u = 0; u < KH; ++u) {
            bf16x8 bn0 = bc0, bn1 = bc1, bn2 = bc2;
            if (u + 1 < KH) {
                const unsigned short* Bu = Blane + (u + 1) * 1536;
                bn0 = *reinterpret_cast<const bf16x8*>(Bu + 0);
                bn1 = *reinterpret_cast<const bf16x8*>(Bu + 512);
                bn2 = *reinterpret_cast<const bf16x8*>(Bu + 1024);
            }
            int off = 64 * s + 32 * rb + m + u;      // 0..270
            int rr  = off - (off >= RING ? RING : 0);
            const unsigned short* rbase = &ring[rr * LSTR];
            bf16x8 a0 = *reinterpret_cast<const bf16x8*>(rbase + (cA + 0) * 8);
            bf16x8 a1 = *reinterpret_cast<const bf16x8*>(rbase + (cA + 2) * 8);
            bf16x8 a2 = *reinterpret_cast<const bf16x8*>(rbase + (cA + 4) * 8);
            acc = __builtin_amdgcn_mfma_f32_32x32x16_bf16(a0, bc0, acc, 0, 0, 0);
            acc = __builtin_amdgcn_mfma_f32_32x32x16_bf16(a1, bc1, acc, 0, 0, 0);
            acc = __builtin_amdgcn_mfma_f32_32x32x16_bf16(a2, bc2, acc, 0, 0, 0);
            bc0 = bn0; bc1 = bn1; bc2 = bn2;
        }

        // ---- (c) convert + ds_write prefetched rows (disjoint ring slots) ----
        if (s + 1 < NSTEP) {
#pragma unroll
            for (int k = 0; k < 3; ++k) {
                if (pval[k]) {
                    uint4 p;
                    p.x = f2bf(p0[k].x) | (f2bf(p0[k].y) << 16);
                    p.y = f2bf(p0[k].z) | (f2bf(p0[k].w) << 16);
                    p.z = f2bf(p1[k].x) | (f2bf(p1[k].y) << 16);
                    p.w = f2bf(p1[k].z) | (f2bf(p1[k].w) << 16);
                    *reinterpret_cast<uint4*>(&ring[pring[k] * LSTR + pcc[k] * 8]) = p;
                }
            }
        }

        // ---- (d) epilogue: C/D col=lane&31, row=(r&3)+8*(r>>2)+4*hi ----
        {
            const int row0 = oy0 + 64 * s + 32 * rb + 4 * hi;
            const int col  = gx0 + 32 * cb + m;
            const bool full = (oy0 + 64 * s + 64 <= OH) && (gx0 + TBC <= OW);
            float* op = out + col;
            if (full) {
#pragma unroll
                for (int r = 0; r < 16; ++r) {
                    int rr = row0 + (r & 3) + 8 * (r >> 2);
                    op[(size_t)rr * OW] = acc[r] + bv;
                }
            } else if (col < OW) {
#pragma unroll
                for (int r = 0; r < 16; ++r) {
                    int rr = row0 + (r & 3) + 8 * (r >> 2);
                    if (rr < OH) op[(size_t)rr * OW] = acc[r] + bv;
                }
            }
        }

        __syncthreads();
    }
}

extern "C" void kernel_launch(void* const* d_in, const int* in_sizes, int n_in,
                              void* d_out, int out_size, void* d_ws, size_t ws_size,
                              hipStream_t stream) {
    const float* x  = (const float*)d_in[0];
    const float* w  = (const float*)d_in[1];
    const float* b  = (const float*)d_in[2];
    float* out = (float*)d_out;
    unsigned short* Bt = (unsigned short*)d_ws;

    build_B<<<96, 256, 0, stream>>>(w, Bt);

    dim3 grid((OW + TBC - 1) / TBC,                       // 32
              (OH + STEP * NSTEP - 1) / (STEP * NSTEP));  // 16
    conv_pipe<<<grid, dim3(512), 0, stream>>>(x, Bt, b, out);
}